// Round 7
// baseline (895.051 us; speedup 1.0000x reference)
//
#include <hip/hip_runtime.h>
#include <hip/hip_bf16.h>
#include <stdint.h>

#define T_TOK 8192
#define DM 1024
#define DF 4096
#define NE 8

typedef __attribute__((ext_vector_type(8))) short short8;
typedef __attribute__((ext_vector_type(8))) unsigned short ushort8;
typedef __attribute__((ext_vector_type(4))) float f32x4;

#define AS1 __attribute__((address_space(1)))
#define AS3 __attribute__((address_space(3)))

static __device__ __forceinline__ unsigned short f2bf(float f) {
  union { float f; unsigned int u; } c; c.f = f;
  unsigned int u = c.u;
  unsigned int r = (u + 0x7FFFu + ((u >> 16) & 1u)) >> 16;
  return (unsigned short)r;
}

static __device__ __forceinline__ float gelu_tanh(float v) {
  float y = 0.7978845608028654f * (v + 0.044715f * v * v * v);
  float ay = fabsf(y);
  float e = __expf(-2.0f * ay);
  float th = (1.0f - e) / (1.0f + e);
  th = copysignf(th, y);
  return 0.5f * v * (1.0f + th);
}

__global__ void k_zero(float* out, int n, int* counts) {
  int gid = blockIdx.x * blockDim.x + threadIdx.x;
  if (gid < NE) counts[gid] = 0;
  for (int i = gid; i < n; i += gridDim.x * blockDim.x) out[i] = 0.f;
}

__global__ void k_probe(float* out, float v, int n) {
  int i = blockIdx.x * blockDim.x + threadIdx.x;
  for (; i < n; i += gridDim.x * blockDim.x) out[i] = v;
}

__global__ void k_cvt_x(const float* __restrict__ x, unsigned short* __restrict__ xb, int n8) {
  int i = blockIdx.x * blockDim.x + threadIdx.x;
  if (i >= n8) return;
  const float4* p = (const float4*)(x + (size_t)i * 8);
  float4 a = p[0], b = p[1];
  ushort4 o0, o1;
  o0.x = f2bf(a.x); o0.y = f2bf(a.y); o0.z = f2bf(a.z); o0.w = f2bf(a.w);
  o1.x = f2bf(b.x); o1.y = f2bf(b.y); o1.z = f2bf(b.z); o1.w = f2bf(b.w);
  ushort4* q = (ushort4*)(xb + (size_t)i * 8);
  q[0] = o0; q[1] = o1;
}

// in: [E][R][C] fp32 -> out: [E][C][R] bf16 (16B stores)
__global__ void k_transpose_bf16(const float* __restrict__ in, unsigned short* __restrict__ out,
                                 int R, int C) {
  __shared__ float tile[64][65];
  int e = blockIdx.z;
  int r0 = blockIdx.y * 64, c0 = blockIdx.x * 64;
  const float* src = in + (size_t)e * R * C;
  unsigned short* dst = out + (size_t)e * R * C;
  int tx = threadIdx.x & 15, ty = threadIdx.x >> 4;
#pragma unroll
  for (int i = 0; i < 4; ++i) {
    int r = ty + i * 16;
    float4 v = *(const float4*)(src + (size_t)(r0 + r) * C + c0 + tx * 4);
    tile[r][tx * 4 + 0] = v.x; tile[r][tx * 4 + 1] = v.y;
    tile[r][tx * 4 + 2] = v.z; tile[r][tx * 4 + 3] = v.w;
  }
  __syncthreads();
  int tx2 = threadIdx.x & 7, ty2 = threadIdx.x >> 3;  // 8 x 32
#pragma unroll
  for (int i = 0; i < 2; ++i) {
    int c = ty2 + i * 32;
    ushort8 o;
#pragma unroll
    for (int j = 0; j < 8; ++j) o[j] = f2bf(tile[tx2 * 8 + j][c]);
    *(ushort8*)(dst + (size_t)(c0 + c) * R + r0 + tx2 * 8) = o;
  }
}

__global__ void k_gate(const float* __restrict__ x, const float* __restrict__ Wg,
                       const float* __restrict__ bg, int* __restrict__ counts,
                       int* __restrict__ btok, float* __restrict__ bw) {
  int wave = threadIdx.x >> 6, lane = threadIdx.x & 63;
  int t = blockIdx.x * 4 + wave;
  double acc[NE];
#pragma unroll
  for (int e = 0; e < NE; ++e) acc[e] = 0.0;
  const float* xr = x + (size_t)t * DM;
  for (int d = lane; d < DM; d += 64) {
    float xv = xr[d];
    const float4* wg = (const float4*)(Wg + (size_t)d * NE);
    float4 w0 = wg[0], w1 = wg[1];
    acc[0] += (double)xv * w0.x; acc[1] += (double)xv * w0.y;
    acc[2] += (double)xv * w0.z; acc[3] += (double)xv * w0.w;
    acc[4] += (double)xv * w1.x; acc[5] += (double)xv * w1.y;
    acc[6] += (double)xv * w1.z; acc[7] += (double)xv * w1.w;
  }
#pragma unroll
  for (int off = 32; off; off >>= 1)
#pragma unroll
    for (int e = 0; e < NE; ++e) acc[e] += __shfl_xor(acc[e], off);
  if (lane == 0) {
    float lg[NE];
#pragma unroll
    for (int e = 0; e < NE; ++e) lg[e] = (float)acc[e] + bg[e];
    float m = lg[0];
#pragma unroll
    for (int e = 1; e < NE; ++e) m = fmaxf(m, lg[e]);
    float s = 0.f, p[NE];
#pragma unroll
    for (int e = 0; e < NE; ++e) { p[e] = expf(lg[e] - m); s += p[e]; }
    float inv = 1.f / s;
    int i1 = 0;
#pragma unroll
    for (int e = 1; e < NE; ++e) if (lg[e] > lg[i1]) i1 = e;
    int i2 = (i1 == 0) ? 1 : 0;
#pragma unroll
    for (int e = 0; e < NE; ++e) if (e != i1 && lg[e] > lg[i2]) i2 = e;
    int pos1 = atomicAdd(&counts[i1], 1);
    btok[i1 * T_TOK + pos1] = t; bw[i1 * T_TOK + pos1] = p[i1] * inv;
    int pos2 = atomicAdd(&counts[i2], 1);
    btok[i2 * T_TOK + pos2] = t; bw[i2 * T_TOK + pos2] = p[i2] * inv;
  }
}

__global__ void k_scan(const int* __restrict__ counts, int* __restrict__ offsets) {
  if (threadIdx.x == 0 && blockIdx.x == 0) {
    int s = 0;
    for (int e = 0; e < NE; ++e) { offsets[e] = s; s += counts[e]; }
  }
}

// ---- 256x256 tile, BK=64, 512 thr (8 waves 2Mx4N), TRUE counted-vmcnt dbuf.
// CRITICAL: four SEPARATELY-DECLARED LDS arrays with literal refs (x2-unrolled
// K-loop) so the memory legalizer can disambiguate in-flight global_load_lds
// writes (other buffer) from ds_reads (current buffer) and does NOT insert
// vmcnt(0) before every compute. Cross-wave ordering by OUR vmcnt(8)+barrier.
// Per half-iter: compute(tile t) -> barrier -> stage(t+2, same bufs) ->
// vmcnt(8) [waits t+1 only] -> barrier. vmcnt never 0 mid-loop.

// stage one K-tile (A: 256x64 rows from srcA, B: 256x64 rows from srcB)
#define STAGE(ks, LA, LB)                                                     \
  do {                                                                        \
    _Pragma("unroll")                                                         \
    for (int i_ = 0; i_ < 4; ++i_) {                                          \
      __builtin_amdgcn_global_load_lds(                                       \
          (const AS1 void*)(srcA[i_] + (size_t)(ks) * 64),                    \
          (AS3 void*)(&LA[ldsg[i_]]), 16, 0, 0);                              \
      __builtin_amdgcn_global_load_lds(                                       \
          (const AS1 void*)(srcB[i_] + (size_t)(ks) * 64),                    \
          (AS3 void*)(&LB[ldsg[i_]]), 16, 0, 0);                              \
    }                                                                         \
  } while (0)

// full-tile compute from literal LDS arrays
#define COMPUTE(LA, LB)                                                       \
  do {                                                                        \
    short8 bfv[2][4];                                                         \
    _Pragma("unroll")                                                         \
    for (int kk = 0; kk < 2; ++kk) {                                          \
      int slot_ = (kk * 4 + khi) ^ (lrow & 7);                                \
      _Pragma("unroll")                                                       \
      for (int n = 0; n < 4; ++n) {                                           \
        int row_ = wn * 64 + n * 16 + lrow;                                   \
        bfv[kk][n] = *(const short8*)(&LB[row_ * 64 + slot_ * 8]);            \
      }                                                                       \
    }                                                                         \
    _Pragma("unroll")                                                         \
    for (int q = 0; q < 4; ++q) {                                             \
      short8 af[2][2];                                                        \
      _Pragma("unroll")                                                       \
      for (int mi = 0; mi < 2; ++mi) {                                        \
        int row_ = wm * 128 + (q * 2 + mi) * 16 + lrow;                       \
        _Pragma("unroll")                                                     \
        for (int kk = 0; kk < 2; ++kk) {                                      \
          int slot_ = (kk * 4 + khi) ^ (lrow & 7);                            \
          af[kk][mi] = *(const short8*)(&LA[row_ * 64 + slot_ * 8]);          \
        }                                                                     \
      }                                                                       \
      __builtin_amdgcn_s_setprio(1);                                          \
      _Pragma("unroll")                                                       \
      for (int kk = 0; kk < 2; ++kk)                                          \
        _Pragma("unroll")                                                     \
        for (int mi = 0; mi < 2; ++mi)                                        \
          _Pragma("unroll")                                                   \
          for (int n = 0; n < 4; ++n)                                         \
            acc[q * 2 + mi][n] = __builtin_amdgcn_mfma_f32_16x16x32_bf16(     \
                af[kk][mi], bfv[kk][n], acc[q * 2 + mi][n], 0, 0, 0);         \
      __builtin_amdgcn_s_setprio(0);                                          \
    }                                                                         \
  } while (0)

#define FENCE asm volatile("" ::: "memory")
#define WAITV8 asm volatile("s_waitcnt vmcnt(8)" ::: "memory")
#define WAITV0 asm volatile("s_waitcnt vmcnt(0)" ::: "memory")

// GEMM1: H[slot][f] = gelu(X[tok] @ W1 + b1), bf16 out.
__global__ __launch_bounds__(512, 1) void k_gemm1(
    const unsigned short* __restrict__ xb,   // [T][DM] bf16
    const unsigned short* __restrict__ w1t,  // [E][DF][DM] bf16
    const float* __restrict__ b1,            // [E][DF]
    const int* __restrict__ counts, const int* __restrict__ offsets,
    const int* __restrict__ btok,
    unsigned short* __restrict__ H,          // [2T][Fchunk] bf16
    int Fchunk, int s0, int gx, int gy) {
  __shared__ __align__(16) unsigned short A0[256 * 64];
  __shared__ __align__(16) unsigned short A1[256 * 64];
  __shared__ __align__(16) unsigned short B0[256 * 64];
  __shared__ __align__(16) unsigned short B1[256 * 64];
  __shared__ int toksh[256];

  int nwg = gx * gy * NE;
  int bid = blockIdx.x;
  int wg = (bid & 7) * (nwg >> 3) + (bid >> 3);
  int e = wg / (gx * gy);
  int rr = wg - e * gx * gy;
  int by = rr / gx;
  int bx = rr - by * gx;

  int cnt = counts[e];
  int m0 = by * 256;
  if (m0 >= cnt) return;
  int eoff = offsets[e];
  int f0 = bx * 256;
  int tid = threadIdx.x;
  int wave = tid >> 6, lane = tid & 63;

  for (int i = tid; i < 256; i += 512) {
    int p = m0 + i; if (p >= cnt) p = cnt - 1;
    toksh[i] = btok[e * T_TOK + p];
  }
  __syncthreads();

  int slin = lane & 7, rsub = lane >> 3;
  int ksl8 = (slin ^ rsub) * 8;

  const unsigned short* srcA[4];
  const unsigned short* srcB[4];
  int ldsg[4];
#pragma unroll
  for (int j = 0; j < 4; ++j) {
    int g = j * 8 + wave;
    int r = g * 8 + rsub;
    srcA[j] = xb + (size_t)toksh[r] * DM + ksl8;
    srcB[j] = w1t + ((size_t)e * DF + s0 + f0 + r) * DM + ksl8;
    ldsg[j] = g * 512;
  }

  int wm = wave >> 2, wn = wave & 3;
  int lrow = lane & 15, khi = lane >> 4;
  f32x4 acc[8][4];
#pragma unroll
  for (int m = 0; m < 8; ++m)
#pragma unroll
    for (int n = 0; n < 4; ++n) acc[m][n] = (f32x4){0.f, 0.f, 0.f, 0.f};

  const int nk = DM / 64;  // 16, even
  STAGE(0, A0, B0);
  STAGE(1, A1, B1);
  WAITV8;                       // tile 0 landed (tile 1 in flight)
  __builtin_amdgcn_s_barrier();
  FENCE;

  for (int t0 = 0; t0 < nk; t0 += 2) {
    COMPUTE(A0, B0);            // tile t0
    FENCE;
    __builtin_amdgcn_s_barrier();
    if (t0 + 2 < nk) { STAGE(t0 + 2, A0, B0); WAITV8; }
    else WAITV0;
    __builtin_amdgcn_s_barrier();
    FENCE;
    COMPUTE(A1, B1);            // tile t0+1
    FENCE;
    __builtin_amdgcn_s_barrier();
    if (t0 + 3 < nk) { STAGE(t0 + 3, A1, B1); WAITV8; }
    else WAITV0;
    __builtin_amdgcn_s_barrier();
    FENCE;
  }

#pragma unroll
  for (int m = 0; m < 8; ++m) {
    int rbase = wm * 128 + m * 16 + khi * 4;
#pragma unroll
    for (int j = 0; j < 4; ++j) {
      int pos = m0 + rbase + j;
      if (pos < cnt) {
        size_t hrow = (size_t)(eoff + pos) * Fchunk;
#pragma unroll
        for (int n = 0; n < 4; ++n) {
          int fl = f0 + wn * 64 + n * 16 + lrow;
          float v = acc[m][n][j] + b1[e * DF + s0 + fl];
          H[hrow + fl] = f2bf(gelu_tanh(v));
        }
      }
    }
  }
}

// GEMM2: out[tok][d] += w * (H[slot] @ W2 + b2)
__global__ __launch_bounds__(512, 1) void k_gemm2(
    const unsigned short* __restrict__ H,    // [2T][Fchunk] bf16
    const unsigned short* __restrict__ w2t,  // [E][DM][DF] bf16
    const float* __restrict__ b2,            // [E][DM]
    const int* __restrict__ counts, const int* __restrict__ offsets,
    const int* __restrict__ btok, const float* __restrict__ bw,
    float* __restrict__ out,
    int Fchunk, int s0, int first, int gx, int gy) {
  __shared__ __align__(16) unsigned short A0[256 * 64];
  __shared__ __align__(16) unsigned short A1[256 * 64];
  __shared__ __align__(16) unsigned short B0[256 * 64];
  __shared__ __align__(16) unsigned short B1[256 * 64];
  __shared__ int toksh[256];
  __shared__ float wsh[256];

  int nwg = gx * gy * NE;
  int bid = blockIdx.x;
  int wg = (bid & 7) * (nwg >> 3) + (bid >> 3);
  int e = wg / (gx * gy);
  int rr = wg - e * gx * gy;
  int by = rr / gx;
  int bx = rr - by * gx;

  int cnt = counts[e];
  int m0 = by * 256;
  if (m0 >= cnt) return;
  int eoff = offsets[e];
  int d0 = bx * 256;
  int tid = threadIdx.x;
  int wave = tid >> 6, lane = tid & 63;

  for (int i = tid; i < 256; i += 512) {
    int p = m0 + i; if (p >= cnt) p = cnt - 1;
    toksh[i] = btok[e * T_TOK + p];
    wsh[i] = bw[e * T_TOK + p];
  }
  __syncthreads();

  int slin = lane & 7, rsub = lane >> 3;
  int ksl8 = (slin ^ rsub) * 8;

  const unsigned short* srcA[4];
  const unsigned short* srcB[4];
  int ldsg[4];
#pragma unroll
  for (int j = 0; j < 4; ++j) {
    int g = j * 8 + wave;
    int r = g * 8 + rsub;
    int p = m0 + r; if (p >= cnt) p = cnt - 1;
    srcA[j] = H + (size_t)(eoff + p) * Fchunk + ksl8;
    srcB[j] = w2t + ((size_t)e * DM + d0 + r) * DF + s0 + ksl8;
    ldsg[j] = g * 512;
  }

  int wm = wave >> 2, wn = wave & 3;
  int lrow = lane & 15, khi = lane >> 4;
  f32x4 acc[8][4];
#pragma unroll
  for (int m = 0; m < 8; ++m)
#pragma unroll
    for (int n = 0; n < 4; ++n) acc[m][n] = (f32x4){0.f, 0.f, 0.f, 0.f};

  const int nk = Fchunk / 64;  // 64 at nsplit=1, even
  STAGE(0, A0, B0);
  STAGE(1, A1, B1);
  WAITV8;
  __builtin_amdgcn_s_barrier();
  FENCE;

  for (int t0 = 0; t0 < nk; t0 += 2) {
    COMPUTE(A0, B0);
    FENCE;
    __builtin_amdgcn_s_barrier();
    if (t0 + 2 < nk) { STAGE(t0 + 2, A0, B0); WAITV8; }
    else WAITV0;
    __builtin_amdgcn_s_barrier();
    FENCE;
    COMPUTE(A1, B1);
    FENCE;
    __builtin_amdgcn_s_barrier();
    if (t0 + 3 < nk) { STAGE(t0 + 3, A1, B1); WAITV8; }
    else WAITV0;
    __builtin_amdgcn_s_barrier();
    FENCE;
  }

#pragma unroll
  for (int m = 0; m < 8; ++m) {
    int rbase = wm * 128 + m * 16 + khi * 4;
#pragma unroll
    for (int j = 0; j < 4; ++j) {
      int lr = rbase + j;
      int pos = m0 + lr;
      if (pos < cnt) {
        int tok = toksh[lr];
        float wgt = wsh[lr];
#pragma unroll
        for (int n = 0; n < 4; ++n) {
          int dc = d0 + wn * 64 + n * 16 + lrow;
          float v = acc[m][n][j];
          if (first) v += b2[e * DM + dc];
          atomicAdd(&out[(size_t)tok * DM + dc], wgt * v);
        }
      }
    }
  }
}

extern "C" void kernel_launch(void* const* d_in, const int* in_sizes, int n_in,
                              void* d_out, int out_size, void* d_ws, size_t ws_size,
                              hipStream_t stream) {
  const float* x  = (const float*)d_in[0];
  const float* Wg = (const float*)d_in[1];
  const float* bg = (const float*)d_in[2];
  const float* W1 = (const float*)d_in[3];
  const float* b1 = (const float*)d_in[4];
  const float* W2 = (const float*)d_in[5];
  const float* b2 = (const float*)d_in[6];
  float* out = (float*)d_out;

  uint8_t* ws = (uint8_t*)d_ws;
  size_t off = 0;
  auto alloc = [&](size_t bytes) {
    size_t o = off;
    off = (off + bytes + 255) & ~(size_t)255;
    return o;
  };
  size_t o_counts = alloc(NE * 4);
  size_t o_offsets = alloc(NE * 4);
  size_t o_btok = alloc((size_t)NE * T_TOK * 4);
  size_t o_bw = alloc((size_t)NE * T_TOK * 4);
  size_t o_xb = alloc((size_t)T_TOK * DM * 2);
  size_t o_w1t = alloc((size_t)NE * DF * DM * 2);
  size_t o_w2t = alloc((size_t)NE * DM * DF * 2);
  size_t fixed = off;

  int nsplit = 0;
  const int splits[5] = {1, 2, 4, 8, 16};
  for (int si = 0; si < 5; ++si) {
    size_t need = fixed + (size_t)2 * T_TOK * (DF / splits[si]) * 2 + 256;
    if (need <= ws_size) { nsplit = splits[si]; break; }
  }
  if (!nsplit) {
    k_probe<<<dim3(1024), dim3(256), 0, stream>>>(out, (float)(double)ws_size, out_size);
    return;
  }
  int Fchunk = DF / nsplit;
  size_t o_h = alloc((size_t)2 * T_TOK * Fchunk * 2);

  int* counts = (int*)(ws + o_counts);
  int* offsets = (int*)(ws + o_offsets);
  int* btok = (int*)(ws + o_btok);
  float* bwp = (float*)(ws + o_bw);
  unsigned short* xb = (unsigned short*)(ws + o_xb);
  unsigned short* w1t = (unsigned short*)(ws + o_w1t);
  unsigned short* w2t = (unsigned short*)(ws + o_w2t);
  unsigned short* Hbuf = (unsigned short*)(ws + o_h);

  k_zero<<<dim3(2048), dim3(256), 0, stream>>>(out, T_TOK * DM, counts);
  k_cvt_x<<<dim3(T_TOK * DM / 8 / 256), dim3(256), 0, stream>>>(x, xb, T_TOK * DM / 8);
  k_transpose_bf16<<<dim3(DF / 64, DM / 64, NE), dim3(256), 0, stream>>>(W1, w1t, DM, DF);
  k_transpose_bf16<<<dim3(DM / 64, DF / 64, NE), dim3(256), 0, stream>>>(W2, w2t, DF, DM);
  k_gate<<<dim3(T_TOK / 4), dim3(256), 0, stream>>>(x, Wg, bg, counts, btok, bwp);
  k_scan<<<dim3(1), dim3(64), 0, stream>>>(counts, offsets);

  int g1x = Fchunk / 256, g1y = T_TOK / 256;
  int g2x = DM / 256, g2y = T_TOK / 256;
  for (int s = 0; s < nsplit; ++s) {
    k_gemm1<<<dim3(g1x * g1y * NE), dim3(512), 0, stream>>>(
        xb, w1t, b1, counts, offsets, btok, Hbuf, Fchunk, s * Fchunk, g1x, g1y);
    k_gemm2<<<dim3(g2x * g2y * NE), dim3(512), 0, stream>>>(
        Hbuf, w2t, b2, counts, offsets, btok, bwp, out, Fchunk, s * Fchunk, s == 0, g2x, g2y);
  }
}

// Round 8
// 731.594 us; speedup vs baseline: 1.2234x; 1.2234x over previous
//
#include <hip/hip_runtime.h>
#include <hip/hip_bf16.h>
#include <stdint.h>

#define T_TOK 8192
#define DM 1024
#define DF 4096
#define NE 8

typedef __attribute__((ext_vector_type(8))) short short8;
typedef __attribute__((ext_vector_type(8))) unsigned short ushort8;
typedef __attribute__((ext_vector_type(4))) float f32x4;

#define AS1 __attribute__((address_space(1)))
#define AS3 __attribute__((address_space(3)))

static __device__ __forceinline__ unsigned short f2bf(float f) {
  union { float f; unsigned int u; } c; c.f = f;
  unsigned int u = c.u;
  unsigned int r = (u + 0x7FFFu + ((u >> 16) & 1u)) >> 16;
  return (unsigned short)r;
}

static __device__ __forceinline__ float gelu_tanh(float v) {
  float y = 0.7978845608028654f * (v + 0.044715f * v * v * v);
  float ay = fabsf(y);
  float e = __expf(-2.0f * ay);
  float th = (1.0f - e) / (1.0f + e);
  th = copysignf(th, y);
  return 0.5f * v * (1.0f + th);
}

__global__ void k_zero(float* out, int n, int* counts) {
  int gid = blockIdx.x * blockDim.x + threadIdx.x;
  if (gid < NE) counts[gid] = 0;
  for (int i = gid; i < n; i += gridDim.x * blockDim.x) out[i] = 0.f;
}

__global__ void k_probe(float* out, float v, int n) {
  int i = blockIdx.x * blockDim.x + threadIdx.x;
  for (; i < n; i += gridDim.x * blockDim.x) out[i] = v;
}

// Fused: bf16 conversion of x + gating (reads x once). One wave per token.
__global__ void k_prep(const float* __restrict__ x, unsigned short* __restrict__ xb,
                       const float* __restrict__ Wg, const float* __restrict__ bg,
                       int* __restrict__ counts, int* __restrict__ btok,
                       float* __restrict__ bw) {
  int wave = threadIdx.x >> 6, lane = threadIdx.x & 63;
  int t = blockIdx.x * 4 + wave;
  const float* xr = x + (size_t)t * DM;
  unsigned short* xo = xb + (size_t)t * DM;
  double acc[NE];
#pragma unroll
  for (int e = 0; e < NE; ++e) acc[e] = 0.0;
#pragma unroll
  for (int i = 0; i < 4; ++i) {
    int d = lane * 4 + i * 256;
    float4 v = *(const float4*)(xr + d);
    ushort4 o;
    o.x = f2bf(v.x); o.y = f2bf(v.y); o.z = f2bf(v.z); o.w = f2bf(v.w);
    *(ushort4*)(xo + d) = o;
    float xv[4] = {v.x, v.y, v.z, v.w};
#pragma unroll
    for (int q = 0; q < 4; ++q) {
      const float4* wg = (const float4*)(Wg + (size_t)(d + q) * NE);
      float4 w0 = wg[0], w1 = wg[1];
      acc[0] += (double)xv[q] * w0.x; acc[1] += (double)xv[q] * w0.y;
      acc[2] += (double)xv[q] * w0.z; acc[3] += (double)xv[q] * w0.w;
      acc[4] += (double)xv[q] * w1.x; acc[5] += (double)xv[q] * w1.y;
      acc[6] += (double)xv[q] * w1.z; acc[7] += (double)xv[q] * w1.w;
    }
  }
#pragma unroll
  for (int off = 32; off; off >>= 1)
#pragma unroll
    for (int e = 0; e < NE; ++e) acc[e] += __shfl_xor(acc[e], off);
  if (lane == 0) {
    float lg[NE];
#pragma unroll
    for (int e = 0; e < NE; ++e) lg[e] = (float)acc[e] + bg[e];
    float m = lg[0];
#pragma unroll
    for (int e = 1; e < NE; ++e) m = fmaxf(m, lg[e]);
    float s = 0.f, p[NE];
#pragma unroll
    for (int e = 0; e < NE; ++e) { p[e] = expf(lg[e] - m); s += p[e]; }
    float inv = 1.f / s;
    int i1 = 0;
#pragma unroll
    for (int e = 1; e < NE; ++e) if (lg[e] > lg[i1]) i1 = e;
    int i2 = (i1 == 0) ? 1 : 0;
#pragma unroll
    for (int e = 0; e < NE; ++e) if (e != i1 && lg[e] > lg[i2]) i2 = e;
    int pos1 = atomicAdd(&counts[i1], 1);
    btok[i1 * T_TOK + pos1] = t; bw[i1 * T_TOK + pos1] = p[i1] * inv;
    int pos2 = atomicAdd(&counts[i2], 1);
    btok[i2 * T_TOK + pos2] = t; bw[i2 * T_TOK + pos2] = p[i2] * inv;
  }
}

// in: [E][R][C] fp32 -> out: [E][C][R] bf16 (16B stores)
__global__ void k_transpose_bf16(const float* __restrict__ in, unsigned short* __restrict__ out,
                                 int R, int C) {
  __shared__ float tile[64][65];
  int e = blockIdx.z;
  int r0 = blockIdx.y * 64, c0 = blockIdx.x * 64;
  const float* src = in + (size_t)e * R * C;
  unsigned short* dst = out + (size_t)e * R * C;
  int tx = threadIdx.x & 15, ty = threadIdx.x >> 4;
#pragma unroll
  for (int i = 0; i < 4; ++i) {
    int r = ty + i * 16;
    float4 v = *(const float4*)(src + (size_t)(r0 + r) * C + c0 + tx * 4);
    tile[r][tx * 4 + 0] = v.x; tile[r][tx * 4 + 1] = v.y;
    tile[r][tx * 4 + 2] = v.z; tile[r][tx * 4 + 3] = v.w;
  }
  __syncthreads();
  int tx2 = threadIdx.x & 7, ty2 = threadIdx.x >> 3;  // 8 x 32
#pragma unroll
  for (int i = 0; i < 2; ++i) {
    int c = ty2 + i * 32;
    ushort8 o;
#pragma unroll
    for (int j = 0; j < 8; ++j) o[j] = f2bf(tile[tx2 * 8 + j][c]);
    *(ushort8*)(dst + (size_t)(c0 + c) * R + r0 + tx2 * 8) = o;
  }
}

__global__ void k_scan(const int* __restrict__ counts, int* __restrict__ offsets) {
  if (threadIdx.x == 0 && blockIdx.x == 0) {
    int s = 0;
    for (int e = 0; e < NE; ++e) { offsets[e] = s; s += counts[e]; }
  }
}

// ---------------- 128x128 tile GEMMs, BK=64, 256 threads (4 waves 2Mx2N) ----
// R6 structure (best: 4 blocks/CU, single-buffer LDS, 2-barrier K-step) with
// stage source pointers HOISTED out of the K-loop: no per-step toksh ds_read /
// 64-bit mul on the load-issue critical path. XCD-chunked grid swizzle kept.

// GEMM1: H[slot][f] = gelu(X[tok] @ W1 + b1), bf16 out.
__global__ __launch_bounds__(256, 4) void k_gemm1(
    const unsigned short* __restrict__ xb,   // [T][DM] bf16
    const unsigned short* __restrict__ w1t,  // [E][DF][DM] bf16
    const float* __restrict__ b1,            // [E][DF]
    const int* __restrict__ counts, const int* __restrict__ offsets,
    const int* __restrict__ btok,
    unsigned short* __restrict__ H,          // [2T][Fchunk] bf16
    int Fchunk, int s0, int gx, int gy) {
  __shared__ __align__(16) unsigned short ldsA[128 * 64];
  __shared__ __align__(16) unsigned short ldsB[128 * 64];
  __shared__ int toksh[128];

  int nwg = gx * gy * NE;
  int bid = blockIdx.x;
  int wg = (bid & 7) * (nwg >> 3) + (bid >> 3);
  int e = wg / (gx * gy);
  int rr = wg - e * gx * gy;
  int by = rr / gx;
  int bx = rr - by * gx;

  int cnt = counts[e];
  int m0 = by * 128;
  if (m0 >= cnt) return;
  int eoff = offsets[e];
  int f0 = bx * 128;
  int tid = threadIdx.x;
  int wave = tid >> 6, lane = tid & 63;

  for (int i = tid; i < 128; i += 256) {
    int p = m0 + i; if (p >= cnt) p = cnt - 1;
    toksh[i] = btok[e * T_TOK + p];
  }
  __syncthreads();

  int slin = lane & 7, rsub = lane >> 3;
  int ksl8 = (slin ^ rsub) * 8;  // pre-swizzled element offset within 64-wide K row

  // hoisted per-thread staging sources (row-group g = j*4+wave, row m = g*8+rsub)
  const unsigned short* srcA[4];
  const unsigned short* srcB[4];
  int ldsg[4];
#pragma unroll
  for (int j = 0; j < 4; ++j) {
    int g = j * 4 + wave;
    int m = g * 8 + rsub;
    srcA[j] = xb + (size_t)toksh[m] * DM + ksl8;
    srcB[j] = w1t + ((size_t)e * DF + s0 + f0 + m) * DM + ksl8;
    ldsg[j] = g * 512;
  }

  auto stage = [&](int ks) {
#pragma unroll
    for (int j = 0; j < 4; ++j) {
      __builtin_amdgcn_global_load_lds((const AS1 void*)(srcA[j] + (size_t)ks * 64),
                                       (AS3 void*)(&ldsA[ldsg[j]]), 16, 0, 0);
      __builtin_amdgcn_global_load_lds((const AS1 void*)(srcB[j] + (size_t)ks * 64),
                                       (AS3 void*)(&ldsB[ldsg[j]]), 16, 0, 0);
    }
  };

  int wm = wave >> 1, wn = wave & 1;
  int lrow = lane & 15, khi = lane >> 4;
  f32x4 acc[4][4];
#pragma unroll
  for (int m = 0; m < 4; ++m)
#pragma unroll
    for (int n = 0; n < 4; ++n) acc[m][n] = (f32x4){0.f, 0.f, 0.f, 0.f};

  auto compute = [&]() {
#pragma unroll
    for (int kk = 0; kk < 2; ++kk) {
      int kslot = kk * 4 + khi;
      short8 af[4], bfv[4];
#pragma unroll
      for (int m = 0; m < 4; ++m) {
        int row = wm * 64 + m * 16 + lrow;
        int slot = kslot ^ (row & 7);
        af[m] = *(const short8*)(&ldsA[row * 64 + slot * 8]);
      }
#pragma unroll
      for (int n = 0; n < 4; ++n) {
        int row = wn * 64 + n * 16 + lrow;
        int slot = kslot ^ (row & 7);
        bfv[n] = *(const short8*)(&ldsB[row * 64 + slot * 8]);
      }
#pragma unroll
      for (int m = 0; m < 4; ++m)
#pragma unroll
        for (int n = 0; n < 4; ++n)
          acc[m][n] = __builtin_amdgcn_mfma_f32_16x16x32_bf16(af[m], bfv[n], acc[m][n], 0, 0, 0);
    }
  };

  const int nk = DM / 64;
  for (int ks = 0; ks < nk; ++ks) {
    stage(ks);
    __syncthreads();
    compute();
    __syncthreads();
  }

#pragma unroll
  for (int m = 0; m < 4; ++m) {
    int rbase = wm * 64 + m * 16 + khi * 4;
#pragma unroll
    for (int j = 0; j < 4; ++j) {
      int pos = m0 + rbase + j;
      if (pos < cnt) {
        size_t hrow = (size_t)(eoff + pos) * Fchunk;
#pragma unroll
        for (int n = 0; n < 4; ++n) {
          int fl = f0 + wn * 64 + n * 16 + lrow;
          float v = acc[m][n][j] + b1[e * DF + s0 + fl];
          H[hrow + fl] = f2bf(gelu_tanh(v));
        }
      }
    }
  }
}

// GEMM2: out[tok][d] += w * (H[slot] @ W2 + b2)
__global__ __launch_bounds__(256, 4) void k_gemm2(
    const unsigned short* __restrict__ H,    // [2T][Fchunk] bf16
    const unsigned short* __restrict__ w2t,  // [E][DM][DF] bf16
    const float* __restrict__ b2,            // [E][DM]
    const int* __restrict__ counts, const int* __restrict__ offsets,
    const int* __restrict__ btok, const float* __restrict__ bw,
    float* __restrict__ out,
    int Fchunk, int s0, int first, int gx, int gy) {
  __shared__ __align__(16) unsigned short ldsA[128 * 64];
  __shared__ __align__(16) unsigned short ldsB[128 * 64];
  __shared__ int toksh[128];
  __shared__ float wsh[128];

  int nwg = gx * gy * NE;
  int bid = blockIdx.x;
  int wg = (bid & 7) * (nwg >> 3) + (bid >> 3);
  int e = wg / (gx * gy);
  int rr = wg - e * gx * gy;
  int by = rr / gx;
  int bx = rr - by * gx;

  int cnt = counts[e];
  int m0 = by * 128;
  if (m0 >= cnt) return;
  int eoff = offsets[e];
  int d0 = bx * 128;
  int tid = threadIdx.x;
  int wave = tid >> 6, lane = tid & 63;

  for (int i = tid; i < 128; i += 256) {
    int p = m0 + i; if (p >= cnt) p = cnt - 1;
    toksh[i] = btok[e * T_TOK + p];
    wsh[i] = bw[e * T_TOK + p];
  }
  __syncthreads();

  int slin = lane & 7, rsub = lane >> 3;
  int ksl8 = (slin ^ rsub) * 8;

  const unsigned short* srcA[4];
  const unsigned short* srcB[4];
  int ldsg[4];
#pragma unroll
  for (int j = 0; j < 4; ++j) {
    int g = j * 4 + wave;
    int m = g * 8 + rsub;
    int p = m0 + m; if (p >= cnt) p = cnt - 1;
    srcA[j] = H + (size_t)(eoff + p) * Fchunk + ksl8;
    srcB[j] = w2t + ((size_t)e * DM + d0 + m) * DF + s0 + ksl8;
    ldsg[j] = g * 512;
  }

  auto stage = [&](int ks) {
#pragma unroll
    for (int j = 0; j < 4; ++j) {
      __builtin_amdgcn_global_load_lds((const AS1 void*)(srcA[j] + (size_t)ks * 64),
                                       (AS3 void*)(&ldsA[ldsg[j]]), 16, 0, 0);
      __builtin_amdgcn_global_load_lds((const AS1 void*)(srcB[j] + (size_t)ks * 64),
                                       (AS3 void*)(&ldsB[ldsg[j]]), 16, 0, 0);
    }
  };

  int wm = wave >> 1, wn = wave & 1;
  int lrow = lane & 15, khi = lane >> 4;
  f32x4 acc[4][4];
#pragma unroll
  for (int m = 0; m < 4; ++m)
#pragma unroll
    for (int n = 0; n < 4; ++n) acc[m][n] = (f32x4){0.f, 0.f, 0.f, 0.f};

  auto compute = [&]() {
#pragma unroll
    for (int kk = 0; kk < 2; ++kk) {
      int kslot = kk * 4 + khi;
      short8 af[4], bfv[4];
#pragma unroll
      for (int m = 0; m < 4; ++m) {
        int row = wm * 64 + m * 16 + lrow;
        int slot = kslot ^ (row & 7);
        af[m] = *(const short8*)(&ldsA[row * 64 + slot * 8]);
      }
#pragma unroll
      for (int n = 0; n < 4; ++n) {
        int row = wn * 64 + n * 16 + lrow;
        int slot = kslot ^ (row & 7);
        bfv[n] = *(const short8*)(&ldsB[row * 64 + slot * 8]);
      }
#pragma unroll
      for (int m = 0; m < 4; ++m)
#pragma unroll
        for (int n = 0; n < 4; ++n)
          acc[m][n] = __builtin_amdgcn_mfma_f32_16x16x32_bf16(af[m], bfv[n], acc[m][n], 0, 0, 0);
    }
  };

  const int nk = Fchunk / 64;
  for (int ks = 0; ks < nk; ++ks) {
    stage(ks);
    __syncthreads();
    compute();
    __syncthreads();
  }

#pragma unroll
  for (int m = 0; m < 4; ++m) {
    int rbase = wm * 64 + m * 16 + khi * 4;
#pragma unroll
    for (int j = 0; j < 4; ++j) {
      int lr = rbase + j;
      int pos = m0 + lr;
      if (pos < cnt) {
        int tok = toksh[lr];
        float wgt = wsh[lr];
#pragma unroll
        for (int n = 0; n < 4; ++n) {
          int dc = d0 + wn * 64 + n * 16 + lrow;
          float v = acc[m][n][j];
          if (first) v += b2[e * DM + dc];
          atomicAdd(&out[(size_t)tok * DM + dc], wgt * v);
        }
      }
    }
  }
}

extern "C" void kernel_launch(void* const* d_in, const int* in_sizes, int n_in,
                              void* d_out, int out_size, void* d_ws, size_t ws_size,
                              hipStream_t stream) {
  const float* x  = (const float*)d_in[0];
  const float* Wg = (const float*)d_in[1];
  const float* bg = (const float*)d_in[2];
  const float* W1 = (const float*)d_in[3];
  const float* b1 = (const float*)d_in[4];
  const float* W2 = (const float*)d_in[5];
  const float* b2 = (const float*)d_in[6];
  float* out = (float*)d_out;

  uint8_t* ws = (uint8_t*)d_ws;
  size_t off = 0;
  auto alloc = [&](size_t bytes) {
    size_t o = off;
    off = (off + bytes + 255) & ~(size_t)255;
    return o;
  };
  size_t o_counts = alloc(NE * 4);
  size_t o_offsets = alloc(NE * 4);
  size_t o_btok = alloc((size_t)NE * T_TOK * 4);
  size_t o_bw = alloc((size_t)NE * T_TOK * 4);
  size_t o_xb = alloc((size_t)T_TOK * DM * 2);
  size_t o_w1t = alloc((size_t)NE * DF * DM * 2);
  size_t o_w2t = alloc((size_t)NE * DM * DF * 2);
  size_t fixed = off;

  int nsplit = 0;
  const int splits[5] = {1, 2, 4, 8, 16};
  for (int si = 0; si < 5; ++si) {
    size_t need = fixed + (size_t)2 * T_TOK * (DF / splits[si]) * 2 + 256;
    if (need <= ws_size) { nsplit = splits[si]; break; }
  }
  if (!nsplit) {
    k_probe<<<dim3(1024), dim3(256), 0, stream>>>(out, (float)(double)ws_size, out_size);
    return;
  }
  int Fchunk = DF / nsplit;
  size_t o_h = alloc((size_t)2 * T_TOK * Fchunk * 2);

  int* counts = (int*)(ws + o_counts);
  int* offsets = (int*)(ws + o_offsets);
  int* btok = (int*)(ws + o_btok);
  float* bwp = (float*)(ws + o_bw);
  unsigned short* xb = (unsigned short*)(ws + o_xb);
  unsigned short* w1t = (unsigned short*)(ws + o_w1t);
  unsigned short* w2t = (unsigned short*)(ws + o_w2t);
  unsigned short* Hbuf = (unsigned short*)(ws + o_h);

  k_zero<<<dim3(2048), dim3(256), 0, stream>>>(out, T_TOK * DM, counts);
  k_prep<<<dim3(T_TOK / 4), dim3(256), 0, stream>>>(x, xb, Wg, bg, counts, btok, bwp);
  k_transpose_bf16<<<dim3(DF / 64, DM / 64, NE), dim3(256), 0, stream>>>(W1, w1t, DM, DF);
  k_transpose_bf16<<<dim3(DM / 64, DF / 64, NE), dim3(256), 0, stream>>>(W2, w2t, DF, DM);
  k_scan<<<dim3(1), dim3(64), 0, stream>>>(counts, offsets);

  int g1x = Fchunk / 128, g1y = T_TOK / 128;
  int g2x = DM / 128, g2y = T_TOK / 128;
  for (int s = 0; s < nsplit; ++s) {
    k_gemm1<<<dim3(g1x * g1y * NE), dim3(256), 0, stream>>>(
        xb, w1t, b1, counts, offsets, btok, Hbuf, Fchunk, s * Fchunk, g1x, g1y);
    k_gemm2<<<dim3(g2x * g2y * NE), dim3(256), 0, stream>>>(
        Hbuf, w2t, b2, counts, offsets, btok, bwp, out, Fchunk, s * Fchunk, s == 0, g2x, g2y);
  }
}